// Round 1
// baseline (187.727 us; speedup 1.0000x reference)
//
#include <hip/hip_runtime.h>
#include <math.h>

// LorentzConv1d: x(16,8192,64) fp32, W(64,316), b(64) -> out(16,8192,64) fp32
// Round 1: correct fp32 baseline. One thread per (b,l); 64 accumulators in
// VGPRs; W pre-transposed into tap-major layout Wt[k][c-1][o] (+ time row at
// f2=315) so inner-loop W reads are lane-uniform -> scalar loads.

#define BSZ   16
#define LLEN  8192
#define CIN   64
#define COUT  64
#define KW    5
#define LINF  316          // (CIN-1)*KW + 1
#define NPOS  (BSZ * LLEN) // 131072

// Wt layout: f2 in [0,315): f2 = k*63 + (c-1), row Wt[f2*64 + o] = W[o*316 + 1 + (c-1)*5 + k]
//            f2 == 315    : time feature row,  Wt[315*64 + o] = W[o*316 + 0]
__global__ void prep_W(const float* __restrict__ W, float* __restrict__ Wt) {
    int i = blockIdx.x * blockDim.x + threadIdx.x;
    if (i >= LINF * COUT) return;
    int f2 = i >> 6;
    int o  = i & 63;
    int src;
    if (f2 == 315) {
        src = o * LINF;                     // f = 0 (time feature)
    } else {
        int k  = f2 / 63;
        int c1 = f2 % 63;
        src = o * LINF + 1 + c1 * KW + k;   // f = 1 + (c-1)*5 + k
    }
    Wt[i] = W[src];
}

__global__ __launch_bounds__(256) void lorentz_conv(
    const float* __restrict__ x, const float* __restrict__ Wt,
    const float* __restrict__ bias, float* __restrict__ out)
{
    int gid = blockIdx.x * 256 + threadIdx.x;   // position index over b*L
    int b = gid >> 13;                          // / 8192
    int l = gid & (LLEN - 1);
    const float* xb = x + (size_t)b * LLEN * CIN;

    float acc[COUT];
    #pragma unroll
    for (int o = 0; o < COUT; ++o) acc[o] = bias[o];

    float tsum = 0.f;

    for (int k = 0; k < KW; ++k) {
        int row = l - 2 + k;                    // PAD = 2
        bool inr = (row >= 0) && (row < LLEN);
        int rowc = min(max(row, 0), LLEN - 1);  // clamp so loads are always safe
        const float4* xr = (const float4*)(xb + (size_t)rowc * CIN);
        const float* wbase = Wt + k * 63 * COUT;

        // chunk 0: channels 0..3 (channel 0 = time)
        float4 v0 = xr[0];
        float tv = inr ? v0.x : 1.0f;           // pad rows: time clamped to sqrt(K)=1
        tsum += tv * tv;
        {
            float vy = inr ? v0.y : 0.f;
            float vz = inr ? v0.z : 0.f;
            float vw = inr ? v0.w : 0.f;
            const float* w0 = wbase;            // c=1 -> c1=0
            #pragma unroll
            for (int o = 0; o < COUT; ++o)
                acc[o] += w0[o] * vy + w0[COUT + o] * vz + w0[2 * COUT + o] * vw;
        }
        // chunks 1..15: channels 4cj .. 4cj+3, all space
        for (int cj = 1; cj < 16; ++cj) {
            float4 v = xr[cj];
            float e0 = inr ? v.x : 0.f;
            float e1 = inr ? v.y : 0.f;
            float e2 = inr ? v.z : 0.f;
            float e3 = inr ? v.w : 0.f;
            const float* wr = wbase + (4 * cj - 1) * COUT;  // c1 = 4cj-1
            #pragma unroll
            for (int o = 0; o < COUT; ++o) {
                acc[o] += wr[o] * e0 + wr[COUT + o] * e1
                        + wr[2 * COUT + o] * e2 + wr[3 * COUT + o] * e3;
            }
        }
    }

    // time feature: t_resc = sqrt(sum t^2 - (KW-1)*K_CURV), K_CURV = 1
    float t_resc = sqrtf(tsum - (float)(KW - 1));
    {
        const float* wt = Wt + 315 * COUT;
        #pragma unroll
        for (int o = 0; o < COUT; ++o) acc[o] += wt[o] * t_resc;
    }

    // output Lorentz: channel 0 of linear output is discarded, replaced by
    // sqrt(sum_{o>=1} y_o^2 + K_CURV)
    float ss = 0.f;
    #pragma unroll
    for (int o = 1; o < COUT; ++o) ss += acc[o] * acc[o];
    acc[0] = sqrtf(ss + 1.0f);

    float4* orow = (float4*)(out + (size_t)gid * COUT);
    #pragma unroll
    for (int cj = 0; cj < 16; ++cj) {
        float4 v;
        v.x = acc[4 * cj + 0];
        v.y = acc[4 * cj + 1];
        v.z = acc[4 * cj + 2];
        v.w = acc[4 * cj + 3];
        orow[cj] = v;
    }
}

extern "C" void kernel_launch(void* const* d_in, const int* in_sizes, int n_in,
                              void* d_out, int out_size, void* d_ws, size_t ws_size,
                              hipStream_t stream) {
    const float* x    = (const float*)d_in[0];
    const float* W    = (const float*)d_in[1];
    const float* bias = (const float*)d_in[2];
    float* out = (float*)d_out;
    float* Wt  = (float*)d_ws;   // needs 316*64*4 = 80896 B of scratch

    hipLaunchKernelGGL(prep_W, dim3((LINF * COUT + 255) / 256), dim3(256), 0, stream,
                       W, Wt);
    hipLaunchKernelGGL(lorentz_conv, dim3(NPOS / 256), dim3(256), 0, stream,
                       x, Wt, bias, out);
}

// Round 2
// 112.578 us; speedup vs baseline: 1.6675x; 1.6675x over previous
//
#include <hip/hip_runtime.h>
#include <math.h>

// LorentzConv1d as bf16-MFMA im2col GEMM.
// x(16,8192,64) fp32, W(64,316), b(64) -> out(16,8192,64) fp32.
// M = 131072 positions, N = 64 outputs, K = 5 taps x 64 ch (ch0 weight = 0,
// time feature t_resc applied in epilogue together with bias).
// Output Lorentz (replace o=0 with sqrt(sum_{o>=1} y^2 + 1)) done in-register
// via shfl reduction over the 16-lane column groups of the MFMA C layout.

#define BSZ   16
#define LLEN  8192
#define CIN   64
#define COUT  64
#define KW    5
#define LINF  316
#define MTILE 128
#define ROWS  (MTILE + 4)   // halo: PAD=2 each side
#define ASTR  72            // LDS row stride in bf16 units (64 + 8 pad) = 144 B, 16B-aligned
#define KB    320           // 5 taps * 64 channels

typedef __attribute__((ext_vector_type(8))) short  short8;   // 8 bf16 = 4 VGPR
typedef __attribute__((ext_vector_type(4))) float  float4v;  // MFMA acc

__device__ inline unsigned short f2bf(float f) {
    unsigned u = __builtin_bit_cast(unsigned int, f);
    u += 0x7FFFu + ((u >> 16) & 1u);      // round-to-nearest-even
    return (unsigned short)(u >> 16);
}

__global__ __launch_bounds__(256) void prep_W(const float* __restrict__ W,
                                              unsigned short* __restrict__ Wb) {
    int i = blockIdx.x * 256 + threadIdx.x;
    if (i >= COUT * KB) return;
    int n   = i / KB;
    int kk  = i - n * KB;
    int tap = kk >> 6;
    int c   = kk & 63;
    float v = (c == 0) ? 0.f : W[n * LINF + 1 + (c - 1) * KW + tap];
    Wb[i] = f2bf(v);
}

__global__ __launch_bounds__(256) void lorentz_mfma(
    const float* __restrict__ x, const unsigned short* __restrict__ Wb,
    const float* __restrict__ W, const float* __restrict__ bias,
    float* __restrict__ out)
{
    __shared__ unsigned short At[ROWS * ASTR];
    __shared__ float tcol[ROWS];
    __shared__ float trsc[MTILE];

    int tid = threadIdx.x;
    int blk = blockIdx.x;
    int b   = blk >> 6;                 // 64 blocks per batch row (8192/128)
    int l0  = (blk & 63) * MTILE;
    const float* xb = x + ((size_t)b * LLEN) * CIN;

    // ---- stage A tile: rows l0-2 .. l0+129, fp32 -> bf16 into LDS ----
    for (int i = tid; i < ROWS * 16; i += 256) {
        int r = i >> 4, ch = i & 15;
        int row = l0 - 2 + r;
        bool inr = (row >= 0) && (row < LLEN);
        int rowc = min(max(row, 0), LLEN - 1);
        float4 v = ((const float4*)(xb + (size_t)rowc * CIN))[ch];
        if (!inr) { v.x = (ch == 0) ? 1.f : 0.f; v.y = 0.f; v.z = 0.f; v.w = 0.f; }
        if (ch == 0) tcol[r] = v.x;     // fp32 time column for t_resc
        ushort4 pk;
        pk.x = f2bf(v.x); pk.y = f2bf(v.y); pk.z = f2bf(v.z); pk.w = f2bf(v.w);
        *(ushort4*)&At[r * ASTR + ch * 4] = pk;
    }
    __syncthreads();

    // ---- per-position rescaled time feature (fp32) ----
    if (tid < MTILE) {
        float s = 0.f;
        #pragma unroll
        for (int k = 0; k < KW; ++k) { float t = tcol[tid + k]; s += t * t; }
        trsc[tid] = sqrtf(s - (float)(KW - 1));
    }
    __syncthreads();

    int lane = tid & 63, wv = tid >> 6;
    int col = lane & 15, quad = lane >> 4;
    int m0 = wv * 32;                   // wave's M offset (2 x 16 subtiles)

    float4v acc[2][4];
    #pragma unroll
    for (int s = 0; s < 2; ++s)
        #pragma unroll
        for (int nt = 0; nt < 4; ++nt)
            acc[s][nt] = (float4v){0.f, 0.f, 0.f, 0.f};

    // ---- GEMM: K = 5 taps x (2 ksteps of 32) ----
    #pragma unroll
    for (int tap = 0; tap < KW; ++tap) {
        #pragma unroll
        for (int ks = 0; ks < 2; ++ks) {
            short8 bfr[4];
            #pragma unroll
            for (int nt = 0; nt < 4; ++nt) {
                int n = nt * 16 + col;  // B fragment: n = lane&15 (+ tile), k = quad*8+j
                bfr[nt] = *(const short8*)(Wb + n * KB + tap * 64 + ks * 32 + quad * 8);
            }
            short8 afr[2];
            #pragma unroll
            for (int s = 0; s < 2; ++s) {
                // A fragment: m = lane&15, k = quad*8+j; input row = pos + tap (LDS row0 = l0-2)
                int row = m0 + s * 16 + col + tap;
                afr[s] = *(const short8*)&At[row * ASTR + ks * 32 + quad * 8];
            }
            #pragma unroll
            for (int s = 0; s < 2; ++s)
                #pragma unroll
                for (int nt = 0; nt < 4; ++nt)
                    acc[s][nt] = __builtin_amdgcn_mfma_f32_16x16x32_bf16(
                        afr[s], bfr[nt], acc[s][nt], 0, 0, 0);
        }
    }

    // ---- epilogue: + bias + t_resc*W_time, then output Lorentz ----
    float bo[4], w0[4];
    #pragma unroll
    for (int nt = 0; nt < 4; ++nt) {
        int o = nt * 16 + col;
        bo[nt] = bias[o];
        w0[nt] = W[o * LINF];           // time-feature weight column of W
    }
    size_t obase = (size_t)blk * MTILE;
    #pragma unroll
    for (int s = 0; s < 2; ++s) {
        float y[4][4];                  // [nt][reg]
        float ssq[4] = {0.f, 0.f, 0.f, 0.f};
        #pragma unroll
        for (int reg = 0; reg < 4; ++reg) {
            float tr = trsc[m0 + s * 16 + quad * 4 + reg];
            #pragma unroll
            for (int nt = 0; nt < 4; ++nt) {
                float v = acc[s][nt][reg] + bo[nt] + tr * w0[nt];
                y[nt][reg] = v;
                bool isc0 = (nt == 0) && (col == 0);   // o = 0: excluded from sum
                ssq[reg] += isc0 ? 0.f : v * v;
            }
        }
        #pragma unroll
        for (int reg = 0; reg < 4; ++reg) {
            #pragma unroll
            for (int msk = 1; msk < 16; msk <<= 1)
                ssq[reg] += __shfl_xor(ssq[reg], msk, 64);  // reduce over 16 cols
            if (col == 0) y[0][reg] = sqrtf(ssq[reg] + 1.f);
        }
        #pragma unroll
        for (int reg = 0; reg < 4; ++reg) {
            size_t pos = obase + m0 + s * 16 + quad * 4 + reg;
            float* orow = out + pos * COUT;
            #pragma unroll
            for (int nt = 0; nt < 4; ++nt)
                orow[nt * 16 + col] = y[nt][reg];
        }
    }
}

extern "C" void kernel_launch(void* const* d_in, const int* in_sizes, int n_in,
                              void* d_out, int out_size, void* d_ws, size_t ws_size,
                              hipStream_t stream) {
    const float* x    = (const float*)d_in[0];
    const float* W    = (const float*)d_in[1];
    const float* bias = (const float*)d_in[2];
    float* out = (float*)d_out;
    unsigned short* Wb = (unsigned short*)d_ws;   // 64*320*2 = 40960 B scratch

    hipLaunchKernelGGL(prep_W, dim3((COUT * KB + 255) / 256), dim3(256), 0, stream,
                       W, Wb);
    hipLaunchKernelGGL(lorentz_mfma, dim3(BSZ * LLEN / MTILE), dim3(256), 0, stream,
                       x, Wb, W, bias, out);
}